// Round 2
// baseline (262.810 us; speedup 1.0000x reference)
//
#include <hip/hip_runtime.h>

#define E0     300000
#define E1     75000
#define NSRC0  50000
#define NDST0  20000
#define NDST1  5000
#define EMB    128
#define HID    256
#define NOUT   16

#define NPB        40     // nodes per embed block (1250 * 40 = 50000 exactly)
#define TILE_SHIFT 12     // 4096-row vocab tiles; tiles 0..12
#define NEMB_BLK   (NSRC0 / NPB)          // 1250

#define X0S  32.0f        // fp8 pre-scale for x0  (undone in layer1 agg)
#define H1S  64.0f        // fp8 pre-scale for h1  (undone in layer2 agg)

typedef __attribute__((ext_vector_type(8))) short bf16x8;   // MFMA A/B frag (4 VGPRs)
typedef __attribute__((ext_vector_type(4))) float f32x4;    // MFMA C/D frag
typedef __attribute__((ext_vector_type(2))) float f32x2;

// ---- bf16 helpers ----
__device__ __forceinline__ unsigned short f2bf(float f) {
    unsigned u = __float_as_uint(f);
    return (unsigned short)((u + 0x7FFFu + ((u >> 16) & 1u)) >> 16);
}
__device__ __forceinline__ unsigned pack2(float a, float b) {
    return (unsigned)f2bf(a) | ((unsigned)f2bf(b) << 16);
}
// ---- fp8 e4m3 helpers (HW cvt) ----
__device__ __forceinline__ unsigned pack4_fp8(float a0, float a1, float a2, float a3) {
    unsigned p = 0;
    p = __builtin_amdgcn_cvt_pk_fp8_f32(a0, a1, p, false);   // bytes 0,1
    p = __builtin_amdgcn_cvt_pk_fp8_f32(a2, a3, p, true);    // bytes 2,3
    return p;
}
__device__ __forceinline__ unsigned char f2fp8(float v) {
    unsigned p = __builtin_amdgcn_cvt_pk_fp8_f32(v, v, 0, false);
    return (unsigned char)(p & 0xFF);
}
// unpack 4 fp8 bytes -> two float2 (packed HW cvt when available)
#if __has_builtin(__builtin_amdgcn_cvt_pk_f32_fp8)
__device__ __forceinline__ f32x2 up_lo(unsigned v) { return __builtin_amdgcn_cvt_pk_f32_fp8(v, false); }
__device__ __forceinline__ f32x2 up_hi(unsigned v) { return __builtin_amdgcn_cvt_pk_f32_fp8(v, true); }
#else
__device__ __forceinline__ f32x2 up_lo(unsigned v) {
    f32x2 r; r.x = __builtin_amdgcn_cvt_f32_fp8(v, 0); r.y = __builtin_amdgcn_cvt_f32_fp8(v, 1); return r;
}
__device__ __forceinline__ f32x2 up_hi(unsigned v) {
    f32x2 r; r.x = __builtin_amdgcn_cvt_f32_fp8(v, 2); r.y = __builtin_amdgcn_cvt_f32_fp8(v, 3); return r;
}
#endif

// accumulate 8 fp8 (one uint2) into 4 f32x2 accumulators
__device__ __forceinline__ void acc8(f32x2* a, uint2 v) {
    a[0] += up_lo(v.x); a[1] += up_hi(v.x);
    a[2] += up_lo(v.y); a[3] += up_hi(v.y);
}

// ---------------- prep: table->fp8, W1^T/W2^T->bf16, degree histograms ----------------
__global__ void prep_kernel(const float* __restrict__ wt, unsigned char* __restrict__ wt8,
                            const float* __restrict__ W1, unsigned short* __restrict__ W1Tb,
                            const float* __restrict__ W2, unsigned short* __restrict__ W2Tb,
                            const int* __restrict__ src0, const int* __restrict__ dst0,
                            const int* __restrict__ src1, const int* __restrict__ dst1,
                            int* cnt0, int* cnt1, int* degO0, int* degO1) {
    int i = blockIdx.x * blockDim.x + threadIdx.x;
    if (i < NSRC0 * EMB / 8) {            // 800000: pack 8 floats -> 8 fp8
        const float4* in = (const float4*)wt;
        float4 v0 = in[i * 2], v1 = in[i * 2 + 1];
        uint2 o;
        o.x = pack4_fp8(v0.x, v0.y, v0.z, v0.w);
        o.y = pack4_fp8(v1.x, v1.y, v1.z, v1.w);
        ((uint2*)wt8)[i] = o;
    }
    if (i < EMB * HID) {                  // W1[128][256] -> W1T bf16 [256][128]
        int n = i & 255, k = i >> 8;
        W1Tb[n * 128 + k] = f2bf(W1[i]);
    }
    if (i < HID * NOUT) {                 // W2[256][16] -> W2T bf16 [16][256]
        int n = i & 15, k = i >> 4;
        W2Tb[n * 256 + k] = f2bf(W2[i]);
    }
    if (i < E0) {
        atomicAdd(&cnt0[dst0[i]], 1);
        atomicAdd(&degO0[src0[i]], 1);
    }
    if (i < E1) {
        atomicAdd(&cnt1[dst1[i]], 1);
        atomicAdd(&degO1[src1[i]], 1);
    }
}

// ---------------- exclusive scan (2 blocks x 1024 threads, own dispatch) --------------
__device__ void scan_body(const int* __restrict__ cnt, int n,
                          int* __restrict__ off, int* __restrict__ cur) {
    __shared__ int sums[1024];
    int t = threadIdx.x;
    int chunk = (n + 1023) / 1024;
    int lo = t * chunk, hi = min(lo + chunk, n);
    int s = 0;
    for (int i = lo; i < hi; ++i) s += cnt[i];
    sums[t] = s;
    __syncthreads();
    for (int d = 1; d < 1024; d <<= 1) {
        int x = (t >= d) ? sums[t - d] : 0;
        __syncthreads();
        sums[t] += x;
        __syncthreads();
    }
    int run = (t == 0) ? 0 : sums[t - 1];
    for (int i = lo; i < hi; ++i) {
        off[i] = run; cur[i] = run;
        run += cnt[i];
    }
    if (t == 1023) off[n] = run;
}

__global__ void scan_kernel(const int* cnt0, int* off0, int* cur0,
                            const int* cnt1, int* off1, int* cur1) {
    if (blockIdx.x == 0) scan_body(cnt0, NDST0, off0, cur0);
    else                 scan_body(cnt1, NDST1, off1, cur1);
}

// ---------------- embed (even blocks) + edge bucket (odd blocks), interleaved ---------
// user_word staged coalesced into LDS (raw[]) -- direct per-node global reads cost
// +33 MB HBM refetch (r1). Wave-parallel ballot tile-sort (13 buckets) from LDS.
// Gather is uint2-vectorized: 16 lanes cover one 128B table row, so each 32-lane
// group load covers TWO sorted positions per instruction (2x MLP vs uint loads);
// even/odd-position partial sums merged by shfl_xor(16) at the end.
__global__ void embed_bucket_kernel(const int* __restrict__ user_word,
                                    const unsigned char* __restrict__ wt8,
                                    const int* __restrict__ degO0,
                                    unsigned char* __restrict__ x0f,
                                    const int* __restrict__ src0, const int* __restrict__ dst0,
                                    const int* __restrict__ src1, const int* __restrict__ dst1,
                                    int* cur0, int* cur1, int* esrc0, int* esrc1) {
    if (blockIdx.x & 1) {                // ---- bucket part (odd blocks) ----
        int i = (blockIdx.x >> 1) * 256 + threadIdx.x;
        if (i < E0) {
            int p = atomicAdd(&cur0[dst0[i]], 1);
            esrc0[p] = src0[i];
        }
        if (i < E1) {
            int p = atomicAdd(&cur1[dst1[i]], 1);
            esrc1[p] = src1[i];
        }
        return;
    }
    // ---- embed part (even blocks) ----
    int eb = blockIdx.x >> 1;            // 0..1249
    __shared__ int raw[NPB * 50];                // 8000 B, coalesced stage
    __shared__ unsigned short srt[NPB * 50];     // 4000 B, tile-sorted word ids
    int t = threadIdx.x;
    int base = eb * NPB * 50;
    for (int j = t; j < NPB * 50; j += 256)
        raw[j] = user_word[base + j];
    __syncthreads();
    {   // ---- wave-parallel tile sort: wave wv sorts nodes wv, wv+4, ..., wv+36 ----
        int wv = t >> 6, j = t & 63;
        unsigned long long lmlt = (1ULL << j) - 1;       // lanes strictly below j
        for (int n = wv; n < NPB; n += 4) {
            int word = 0, b = 16;                        // j>=50 lanes: bucket 16 (inert)
            if (j < 50) { word = raw[n * 50 + j]; b = word >> TILE_SHIFT; }
            int pos = 0;
            #pragma unroll
            for (int bb = 0; bb < 13; ++bb) {
                unsigned long long m = __ballot(b == bb);
                if (bb < b)       pos += __popcll(m);
                else if (bb == b) pos += __popcll(m & lmlt);
            }
            if (j < 50) srt[n * 50 + pos] = (unsigned short)word;
        }
    }
    __syncthreads();
    int g = t >> 5, l = t & 31;                   // 8 groups of 32 lanes
    int sub = l >> 4, c8 = l & 15;                // half-group 0/1, uint2 column
    const uint2* wt2 = (const uint2*)wt8;         // row = 16 uint2 (128 B)
    const unsigned short* id[5];
    #pragma unroll
    for (int k = 0; k < 5; ++k) id[k] = srt + (g + 8 * k) * 50 + sub;
    f32x2 acc[5][4];
    #pragma unroll
    for (int k = 0; k < 5; ++k)
        #pragma unroll
        for (int q = 0; q < 4; ++q) acc[k][q] = (f32x2){0.f, 0.f};
    // pair loop: pair p covers sorted positions 2p+sub; unroll 2 -> 10 uint2 in flight
    int p = 0;
    for (; p + 1 < 25; p += 2) {
        uint2 va[5], vb[5];
        #pragma unroll
        for (int k = 0; k < 5; ++k) va[k] = wt2[(int)id[k][2 * p] * 16 + c8];
        #pragma unroll
        for (int k = 0; k < 5; ++k) vb[k] = wt2[(int)id[k][2 * p + 2] * 16 + c8];
        #pragma unroll
        for (int k = 0; k < 5; ++k) { acc8(acc[k], va[k]); acc8(acc[k], vb[k]); }
    }
    {   // tail pair 24 (positions 48,49)
        uint2 v[5];
        #pragma unroll
        for (int k = 0; k < 5; ++k) v[k] = wt2[(int)id[k][48] * 16 + c8];
        #pragma unroll
        for (int k = 0; k < 5; ++k) acc8(acc[k], v[k]);
    }
    // merge even/odd-position halves (lane <-> lane^16, stays within 32-group)
    #pragma unroll
    for (int k = 0; k < 5; ++k)
        #pragma unroll
        for (int q = 0; q < 4; ++q) {
            acc[k][q].x += __shfl_xor(acc[k][q].x, 16);
            acc[k][q].y += __shfl_xor(acc[k][q].y, 16);
        }
    if (sub == 0) {
        #pragma unroll
        for (int k = 0; k < 5; ++k) {
            int node = eb * NPB + g + 8 * k;
            float s = rsqrtf(fmaxf((float)degO0[node], 1.0f)) * (0.02f * X0S); // 1/50 mean
            uint2 o;
            o.x = pack4_fp8(acc[k][0].x * s, acc[k][0].y * s, acc[k][1].x * s, acc[k][1].y * s);
            o.y = pack4_fp8(acc[k][2].x * s, acc[k][2].y * s, acc[k][3].x * s, acc[k][3].y * s);
            ((uint2*)x0f)[node * 16 + c8] = o;
        }
    }
}

// ---------------- layer1: agg (16 waves, 1 dst/wave) + MFMA GEMM, fused --------------
// 1024 threads = 16 waves; wave w aggregates dst row0+w (full TLP: 20000 waves total,
// same as standalone agg1 -- r8's failure was 4 waves x 4 serial rows). LDS A-tile
// [16][136] bf16 (pad 8 -> b128 reads are 2-way bank-aliased = free). After one
// barrier, wave w computes col-tile w (16 cols) of the 16x256 output via 4 MFMA.
__global__ void layer1_kernel(const int* __restrict__ off0, const int* __restrict__ esrc0,
                              const unsigned char* __restrict__ x0f,
                              const int* __restrict__ degO1,
                              const unsigned short* __restrict__ W1Tb,
                              const float* __restrict__ b1,
                              unsigned char* __restrict__ h1f) {
    __shared__ unsigned short A[16 * 136];   // bf16, stride 136 (272B)
    __shared__ float s_out[16];
    int t = threadIdx.x;
    int row0 = blockIdx.x * 16;
    int w = t >> 6, lane = t & 63;
    int half = lane >> 5, l = lane & 31;
    if (t < 16) s_out[t] = rsqrtf(fmaxf((float)degO1[row0 + t], 1.0f)) * H1S;
    // ---- agg phase: wave w -> dst row0 + w ----
    {
        int d = row0 + w;
        int lo = off0[d], hi = off0[d + 1];
        const unsigned* x4 = (const unsigned*)x0f;     // row = 32 uints
        f32x2 a01a = {0.f, 0.f}, a23a = {0.f, 0.f};
        f32x2 a01b = {0.f, 0.f}, a23b = {0.f, 0.f};
        int j = lo + half;
        for (; j + 2 < hi; j += 4) {                   // 4 loads in flight/wave
            unsigned va = x4[esrc0[j] * 32 + l];
            unsigned vb = x4[esrc0[j + 2] * 32 + l];
            a01a += up_lo(va); a23a += up_hi(va);
            a01b += up_lo(vb); a23b += up_hi(vb);
        }
        if (j < hi) {
            unsigned v = x4[esrc0[j] * 32 + l];
            a01a += up_lo(v); a23a += up_hi(v);
        }
        f32x2 a01 = a01a + a01b, a23 = a23a + a23b;
        a01.x += __shfl_down(a01.x, 32); a01.y += __shfl_down(a01.y, 32);
        a23.x += __shfl_down(a23.x, 32); a23.y += __shfl_down(a23.y, 32);
        if (half == 0) {
            float sc = rsqrtf(fmaxf((float)(hi - lo), 1.0f)) * (1.0f / X0S);
            uint2 o; o.x = pack2(a01.x * sc, a01.y * sc); o.y = pack2(a23.x * sc, a23.y * sc);
            *(uint2*)(A + w * 136 + l * 4) = o;        // 4 bf16 per lane
        }
    }
    __syncthreads();
    // ---- gemm phase: wave w -> col tile w (cols 16w..16w+15) ----
    int m = lane & 15, quad = lane >> 4;
    bf16x8 afr[4];
    #pragma unroll
    for (int ks = 0; ks < 4; ++ks)
        afr[ks] = *(const bf16x8*)(A + m * 136 + quad * 8 + ks * 32);
    int gcol0 = w * 16;
    const unsigned short* bbase = W1Tb + (gcol0 + m) * 128 + quad * 8;
    f32x4 acc = {0.f, 0.f, 0.f, 0.f};
    #pragma unroll
    for (int ks = 0; ks < 4; ++ks) {
        bf16x8 bfr = *(const bf16x8*)(bbase + ks * 32);
        acc = __builtin_amdgcn_mfma_f32_16x16x32_bf16(afr[ks], bfr, acc, 0, 0, 0);
    }
    int gcol = gcol0 + m;
    float bb = b1[gcol];
    #pragma unroll
    for (int reg = 0; reg < 4; ++reg) {
        int row = quad * 4 + reg;
        h1f[(row0 + row) * 256 + gcol] = f2fp8(fmaxf(acc[reg] + bb, 0.f) * s_out[row]);
    }
}

// ---------------- layer2: agg (16 waves, 1 dst/wave) + MFMA GEMM (+ labels), fused ----
__global__ void layer2_kernel(const int* __restrict__ off1, const int* __restrict__ esrc1,
                              const unsigned char* __restrict__ h1f,
                              const unsigned short* __restrict__ W2Tb,
                              const float* __restrict__ b2,
                              const int* __restrict__ labels,
                              float* __restrict__ out) {
    __shared__ unsigned short A[16 * 264];   // bf16 rows of 256, stride 264 (528B)
    int t = threadIdx.x;
    int row0 = blockIdx.x * 16;
    int w = t >> 6, lane = t & 63;
    // ---- agg phase: wave w -> dst row0 + w (64 lanes x uint = 256 fp8 row) ----
    {
        int d = row0 + w;
        f32x2 a01 = {0.f, 0.f}, a23 = {0.f, 0.f};
        float sc = 0.f;
        if (d < NDST1) {
            int lo = off1[d], hi = off1[d + 1];
            const unsigned* h4 = (const unsigned*)h1f;     // row = 64 uints
            int j = lo;
            for (; j + 3 < hi; j += 4) {                   // 4 loads in flight
                unsigned v0 = h4[esrc1[j] * 64 + lane];
                unsigned v1 = h4[esrc1[j + 1] * 64 + lane];
                unsigned v2 = h4[esrc1[j + 2] * 64 + lane];
                unsigned v3 = h4[esrc1[j + 3] * 64 + lane];
                a01 += up_lo(v0) + up_lo(v1) + up_lo(v2) + up_lo(v3);
                a23 += up_hi(v0) + up_hi(v1) + up_hi(v2) + up_hi(v3);
            }
            for (; j < hi; ++j) {
                unsigned v = h4[esrc1[j] * 64 + lane];
                a01 += up_lo(v); a23 += up_hi(v);
            }
            sc = rsqrtf(fmaxf((float)(hi - lo), 1.0f)) * (1.0f / H1S);
        }
        uint2 o; o.x = pack2(a01.x * sc, a01.y * sc); o.y = pack2(a23.x * sc, a23.y * sc);
        *(uint2*)(A + w * 264 + lane * 4) = o;
    }
    __syncthreads();
    if (w == 0) {                        // ---- gemm phase: single 16x16 tile ----
        int m = lane & 15, quad = lane >> 4;
        const unsigned short* bbase = W2Tb + m * 256 + quad * 8;
        f32x4 acc = {0.f, 0.f, 0.f, 0.f};
        #pragma unroll
        for (int ks = 0; ks < 8; ++ks) {
            bf16x8 af = *(const bf16x8*)(A + m * 264 + quad * 8 + ks * 32);
            bf16x8 bf = *(const bf16x8*)(bbase + ks * 32);
            acc = __builtin_amdgcn_mfma_f32_16x16x32_bf16(af, bf, acc, 0, 0, 0);
        }
        float bb = b2[m];
        #pragma unroll
        for (int reg = 0; reg < 4; ++reg) {
            int row = row0 + quad * 4 + reg;
            if (row < NDST1)
                out[row * NOUT + m] = fmaxf(acc[reg] + bb, 0.f);
        }
        if (lane < 16 && row0 + lane < NDST1)
            out[NDST1 * NOUT + row0 + lane] = (float)labels[row0 + lane];
    }
}

extern "C" void kernel_launch(void* const* d_in, const int* in_sizes, int n_in,
                              void* d_out, int out_size, void* d_ws, size_t ws_size,
                              hipStream_t stream) {
    const int*   user_word  = (const int*)d_in[0];
    const int*   labels     = (const int*)d_in[1];
    const int*   src0       = (const int*)d_in[2];
    const int*   dst0       = (const int*)d_in[3];
    const int*   src1       = (const int*)d_in[4];
    const int*   dst1       = (const int*)d_in[5];
    const float* word_table = (const float*)d_in[6];
    const float* W1         = (const float*)d_in[7];
    const float* b1         = (const float*)d_in[8];
    const float* W2         = (const float*)d_in[9];
    const float* b2         = (const float*)d_in[10];

    int* iws = (int*)d_ws;
    int* cnt0  = iws;            // 20000  ┐
    int* cnt1  = iws + 20000;    //  5000  │ zeroed (95000 ints)
    int* degO0 = iws + 25000;    // 50000  │
    int* degO1 = iws + 75000;    // 20000  ┘
    int* off0  = iws + 95000;    // 20001
    int* off1  = iws + 115001;   //  5001
    int* cur0  = iws + 120002;   // 20000
    int* cur1  = iws + 140002;   //  5000
    int* esrc0 = iws + 145002;   // 300000
    int* esrc1 = iws + 445002;   // 75000   (end 520002; pad to 520004)
    unsigned char*  wt8  = (unsigned char*)(iws + 520004);   // 6.4M fp8  = 1.6M ints
    unsigned char*  x0f  = (unsigned char*)(iws + 2120004);  // 6.4M fp8  = 1.6M ints
    unsigned char*  h1f  = (unsigned char*)(iws + 3720004);  // 5.12M fp8 = 1.28M ints
    unsigned short* W1Tb = (unsigned short*)(iws + 5000004); // 32768 bf16 = 8192 ints
    unsigned short* W2Tb = (unsigned short*)(iws + 5008196); // 4096 bf16 (end ≈ 20 MB)

    hipMemsetAsync(iws, 0, 95000 * sizeof(int), stream);

    prep_kernel<<<(NSRC0 * EMB / 8 + 255) / 256, 256, 0, stream>>>(
        word_table, wt8, W1, W1Tb, W2, W2Tb,
        src0, dst0, src1, dst1, cnt0, cnt1, degO0, degO1);
    scan_kernel<<<2, 1024, 0, stream>>>(cnt0, off0, cur0, cnt1, off1, cur1);
    embed_bucket_kernel<<<NEMB_BLK * 2, 256, 0, stream>>>(
        user_word, wt8, degO0, x0f,
        src0, dst0, src1, dst1, cur0, cur1, esrc0, esrc1);
    layer1_kernel<<<NDST0 / 16, 1024, 0, stream>>>(off0, esrc0, x0f, degO1, W1Tb, b1, h1f);
    layer2_kernel<<<(NDST1 + 15) / 16, 1024, 0, stream>>>(off1, esrc1, h1f, W2Tb, b2,
                                                          labels, (float*)d_out);
}

// Round 3
// 258.599 us; speedup vs baseline: 1.0163x; 1.0163x over previous
//
#include <hip/hip_runtime.h>

#define E0     300000
#define E1     75000
#define NSRC0  50000
#define NDST0  20000
#define NDST1  5000
#define EMB    128
#define HID    256
#define NOUT   16

#define NPB        40     // nodes per embed block (1250 * 40 = 50000 exactly)
#define TILE_SHIFT 12     // 4096-row vocab tiles; tiles 0..12
#define NEMB_BLK   (NSRC0 / NPB)          // 1250

#define X0S  32.0f        // fp8 pre-scale for x0  (undone in layer1 agg)
#define H1S  64.0f        // fp8 pre-scale for h1  (undone in layer2 agg)

typedef __attribute__((ext_vector_type(8))) short bf16x8;   // MFMA A/B frag (4 VGPRs)
typedef __attribute__((ext_vector_type(4))) float f32x4;    // MFMA C/D frag
typedef __attribute__((ext_vector_type(2))) float f32x2;

// ---- bf16 helpers ----
__device__ __forceinline__ unsigned short f2bf(float f) {
    unsigned u = __float_as_uint(f);
    return (unsigned short)((u + 0x7FFFu + ((u >> 16) & 1u)) >> 16);
}
__device__ __forceinline__ unsigned pack2(float a, float b) {
    return (unsigned)f2bf(a) | ((unsigned)f2bf(b) << 16);
}
// ---- fp8 e4m3 helpers (HW cvt) ----
__device__ __forceinline__ unsigned pack4_fp8(float a0, float a1, float a2, float a3) {
    unsigned p = 0;
    p = __builtin_amdgcn_cvt_pk_fp8_f32(a0, a1, p, false);   // bytes 0,1
    p = __builtin_amdgcn_cvt_pk_fp8_f32(a2, a3, p, true);    // bytes 2,3
    return p;
}
__device__ __forceinline__ unsigned char f2fp8(float v) {
    unsigned p = __builtin_amdgcn_cvt_pk_fp8_f32(v, v, 0, false);
    return (unsigned char)(p & 0xFF);
}
// unpack 4 fp8 bytes -> two float2 (packed HW cvt when available)
#if __has_builtin(__builtin_amdgcn_cvt_pk_f32_fp8)
__device__ __forceinline__ f32x2 up_lo(unsigned v) { return __builtin_amdgcn_cvt_pk_f32_fp8(v, false); }
__device__ __forceinline__ f32x2 up_hi(unsigned v) { return __builtin_amdgcn_cvt_pk_f32_fp8(v, true); }
#else
__device__ __forceinline__ f32x2 up_lo(unsigned v) {
    f32x2 r; r.x = __builtin_amdgcn_cvt_f32_fp8(v, 0); r.y = __builtin_amdgcn_cvt_f32_fp8(v, 1); return r;
}
__device__ __forceinline__ f32x2 up_hi(unsigned v) {
    f32x2 r; r.x = __builtin_amdgcn_cvt_f32_fp8(v, 2); r.y = __builtin_amdgcn_cvt_f32_fp8(v, 3); return r;
}
#endif

// ---------------- prep: table->fp8, W1^T/W2^T->bf16, degree histograms ----------------
__global__ void prep_kernel(const float* __restrict__ wt, unsigned char* __restrict__ wt8,
                            const float* __restrict__ W1, unsigned short* __restrict__ W1Tb,
                            const float* __restrict__ W2, unsigned short* __restrict__ W2Tb,
                            const int* __restrict__ src0, const int* __restrict__ dst0,
                            const int* __restrict__ src1, const int* __restrict__ dst1,
                            int* cnt0, int* cnt1, int* degO0, int* degO1) {
    int i = blockIdx.x * blockDim.x + threadIdx.x;
    if (i < NSRC0 * EMB / 8) {            // 800000: pack 8 floats -> 8 fp8
        const float4* in = (const float4*)wt;
        float4 v0 = in[i * 2], v1 = in[i * 2 + 1];
        uint2 o;
        o.x = pack4_fp8(v0.x, v0.y, v0.z, v0.w);
        o.y = pack4_fp8(v1.x, v1.y, v1.z, v1.w);
        ((uint2*)wt8)[i] = o;
    }
    if (i < EMB * HID) {                  // W1[128][256] -> W1T bf16 [256][128]
        int n = i & 255, k = i >> 8;
        W1Tb[n * 128 + k] = f2bf(W1[i]);
    }
    if (i < HID * NOUT) {                 // W2[256][16] -> W2T bf16 [16][256]
        int n = i & 15, k = i >> 4;
        W2Tb[n * 256 + k] = f2bf(W2[i]);
    }
    if (i < E0) {
        atomicAdd(&cnt0[dst0[i]], 1);
        atomicAdd(&degO0[src0[i]], 1);
    }
    if (i < E1) {
        atomicAdd(&cnt1[dst1[i]], 1);
        atomicAdd(&degO1[src1[i]], 1);
    }
}

// ---------------- exclusive scan (2 blocks x 1024 threads, own dispatch) --------------
__device__ void scan_body(const int* __restrict__ cnt, int n,
                          int* __restrict__ off, int* __restrict__ cur) {
    __shared__ int sums[1024];
    int t = threadIdx.x;
    int chunk = (n + 1023) / 1024;
    int lo = t * chunk, hi = min(lo + chunk, n);
    int s = 0;
    for (int i = lo; i < hi; ++i) s += cnt[i];
    sums[t] = s;
    __syncthreads();
    for (int d = 1; d < 1024; d <<= 1) {
        int x = (t >= d) ? sums[t - d] : 0;
        __syncthreads();
        sums[t] += x;
        __syncthreads();
    }
    int run = (t == 0) ? 0 : sums[t - 1];
    for (int i = lo; i < hi; ++i) {
        off[i] = run; cur[i] = run;
        run += cnt[i];
    }
    if (t == 1023) off[n] = run;
}

__global__ void scan_kernel(const int* cnt0, int* off0, int* cur0,
                            const int* cnt1, int* off1, int* cur1) {
    if (blockIdx.x == 0) scan_body(cnt0, NDST0, off0, cur0);
    else                 scan_body(cnt1, NDST1, off1, cur1);
}

// ---------------- embed (even blocks) + edge bucket (odd blocks), interleaved ---------
// Staging: user_word -> LDS coalesced int4 (direct per-node reads cost +33MB HBM, r1).
// Sort: wave-parallel ballot counting-sort, 13 tile buckets, conflict-free (r1).
// Gather: uint per lane (32 lanes = one full 128B row per instruction), 4 positions x
// 5 nodes unrolled = 20 independent row-loads in flight per wave (r0-r2 all had 10;
// latency-bound at ~2 resident blocks/CU, so per-wave MLP is the lever).
__global__ void embed_bucket_kernel(const int* __restrict__ user_word,
                                    const unsigned char* __restrict__ wt8,
                                    const int* __restrict__ degO0,
                                    unsigned char* __restrict__ x0f,
                                    const int* __restrict__ src0, const int* __restrict__ dst0,
                                    const int* __restrict__ src1, const int* __restrict__ dst1,
                                    int* cur0, int* cur1, int* esrc0, int* esrc1) {
    if (blockIdx.x & 1) {                // ---- bucket part (odd blocks) ----
        int i = (blockIdx.x >> 1) * 256 + threadIdx.x;
        if (i < E0) {
            int p = atomicAdd(&cur0[dst0[i]], 1);
            esrc0[p] = src0[i];
        }
        if (i < E1) {
            int p = atomicAdd(&cur1[dst1[i]], 1);
            esrc1[p] = src1[i];
        }
        return;
    }
    // ---- embed part (even blocks) ----
    int eb = blockIdx.x >> 1;            // 0..1249
    __shared__ int raw[NPB * 50];                // 8000 B, coalesced stage
    __shared__ unsigned short srt[NPB * 50];     // 4000 B, tile-sorted word ids
    int t = threadIdx.x;
    {   // int4-coalesced stage: 500 int4 = 2000 ints (base is 16B-aligned: eb*8000B)
        const int4* uw4 = (const int4*)(user_word + eb * NPB * 50);
        int4* raw4 = (int4*)raw;
        for (int j = t; j < NPB * 50 / 4; j += 256)
            raw4[j] = uw4[j];
    }
    __syncthreads();
    {   // ---- wave-parallel tile sort: wave wv sorts nodes wv, wv+4, ..., wv+36 ----
        int wv = t >> 6, j = t & 63;
        unsigned long long lmlt = (1ULL << j) - 1;       // lanes strictly below j
        for (int n = wv; n < NPB; n += 4) {
            int word = 0, b = 16;                        // j>=50 lanes: bucket 16 (inert)
            if (j < 50) { word = raw[n * 50 + j]; b = word >> TILE_SHIFT; }
            int pos = 0;
            #pragma unroll
            for (int bb = 0; bb < 13; ++bb) {
                unsigned long long m = __ballot(b == bb);
                if (bb < b)       pos += __popcll(m);
                else if (bb == b) pos += __popcll(m & lmlt);
            }
            if (j < 50) srt[n * 50 + pos] = (unsigned short)word;
        }
    }
    __syncthreads();
    int g = t >> 5, l = t & 31;                   // 8 groups of 32 lanes
    const unsigned* wt4 = (const unsigned*)wt8;   // row = 32 uints
    const unsigned short* id[5];
    #pragma unroll
    for (int k = 0; k < 5; ++k) id[k] = srt + (g + 8 * k) * 50;
    f32x2 a01[5], a23[5];
    #pragma unroll
    for (int k = 0; k < 5; ++k) { a01[k] = (f32x2){0.f, 0.f}; a23[k] = (f32x2){0.f, 0.f}; }
    int j = 0;
    for (; j + 3 < 50; j += 4) {                  // 4 positions x 5 nodes = 20 in flight
        unsigned v[5][4];
        #pragma unroll
        for (int k = 0; k < 5; ++k)
            #pragma unroll
            for (int u = 0; u < 4; ++u)
                v[k][u] = wt4[(int)id[k][j + u] * 32 + l];
        #pragma unroll
        for (int k = 0; k < 5; ++k)
            #pragma unroll
            for (int u = 0; u < 4; ++u) {
                a01[k] += up_lo(v[k][u]); a23[k] += up_hi(v[k][u]);
            }
    }
    {   // tail: positions 48,49
        unsigned v[5][2];
        #pragma unroll
        for (int k = 0; k < 5; ++k)
            #pragma unroll
            for (int u = 0; u < 2; ++u)
                v[k][u] = wt4[(int)id[k][48 + u] * 32 + l];
        #pragma unroll
        for (int k = 0; k < 5; ++k)
            #pragma unroll
            for (int u = 0; u < 2; ++u) {
                a01[k] += up_lo(v[k][u]); a23[k] += up_hi(v[k][u]);
            }
    }
    #pragma unroll
    for (int k = 0; k < 5; ++k) {
        int node = eb * NPB + g + k * 8;
        float s = rsqrtf(fmaxf((float)degO0[node], 1.0f)) * (0.02f * X0S); // 1/50 mean
        ((unsigned*)x0f)[node * 32 + l] =
            pack4_fp8(a01[k].x * s, a01[k].y * s, a23[k].x * s, a23[k].y * s);
    }
}

// ---------------- layer1: agg (16 waves, 1 dst/wave) + MFMA GEMM, fused --------------
// 1024 threads = 16 waves; wave w aggregates dst row0+w (full TLP: 20000 waves total,
// same as standalone agg1 -- r8's failure was 4 waves x 4 serial rows). LDS A-tile
// [16][136] bf16 (pad 8 -> b128 reads are 2-way bank-aliased = free). After one
// barrier, wave w computes col-tile w (16 cols) of the 16x256 output via 4 MFMA.
__global__ void layer1_kernel(const int* __restrict__ off0, const int* __restrict__ esrc0,
                              const unsigned char* __restrict__ x0f,
                              const int* __restrict__ degO1,
                              const unsigned short* __restrict__ W1Tb,
                              const float* __restrict__ b1,
                              unsigned char* __restrict__ h1f) {
    __shared__ unsigned short A[16 * 136];   // bf16, stride 136 (272B)
    __shared__ float s_out[16];
    int t = threadIdx.x;
    int row0 = blockIdx.x * 16;
    int w = t >> 6, lane = t & 63;
    int half = lane >> 5, l = lane & 31;
    if (t < 16) s_out[t] = rsqrtf(fmaxf((float)degO1[row0 + t], 1.0f)) * H1S;
    // ---- agg phase: wave w -> dst row0 + w ----
    {
        int d = row0 + w;
        int lo = off0[d], hi = off0[d + 1];
        const unsigned* x4 = (const unsigned*)x0f;     // row = 32 uints
        f32x2 a01a = {0.f, 0.f}, a23a = {0.f, 0.f};
        f32x2 a01b = {0.f, 0.f}, a23b = {0.f, 0.f};
        int j = lo + half;
        for (; j + 2 < hi; j += 4) {                   // 4 loads in flight/wave
            unsigned va = x4[esrc0[j] * 32 + l];
            unsigned vb = x4[esrc0[j + 2] * 32 + l];
            a01a += up_lo(va); a23a += up_hi(va);
            a01b += up_lo(vb); a23b += up_hi(vb);
        }
        if (j < hi) {
            unsigned v = x4[esrc0[j] * 32 + l];
            a01a += up_lo(v); a23a += up_hi(v);
        }
        f32x2 a01 = a01a + a01b, a23 = a23a + a23b;
        a01.x += __shfl_down(a01.x, 32); a01.y += __shfl_down(a01.y, 32);
        a23.x += __shfl_down(a23.x, 32); a23.y += __shfl_down(a23.y, 32);
        if (half == 0) {
            float sc = rsqrtf(fmaxf((float)(hi - lo), 1.0f)) * (1.0f / X0S);
            uint2 o; o.x = pack2(a01.x * sc, a01.y * sc); o.y = pack2(a23.x * sc, a23.y * sc);
            *(uint2*)(A + w * 136 + l * 4) = o;        // 4 bf16 per lane
        }
    }
    __syncthreads();
    // ---- gemm phase: wave w -> col tile w (cols 16w..16w+15) ----
    int m = lane & 15, quad = lane >> 4;
    bf16x8 afr[4];
    #pragma unroll
    for (int ks = 0; ks < 4; ++ks)
        afr[ks] = *(const bf16x8*)(A + m * 136 + quad * 8 + ks * 32);
    int gcol0 = w * 16;
    const unsigned short* bbase = W1Tb + (gcol0 + m) * 128 + quad * 8;
    f32x4 acc = {0.f, 0.f, 0.f, 0.f};
    #pragma unroll
    for (int ks = 0; ks < 4; ++ks) {
        bf16x8 bfr = *(const bf16x8*)(bbase + ks * 32);
        acc = __builtin_amdgcn_mfma_f32_16x16x32_bf16(afr[ks], bfr, acc, 0, 0, 0);
    }
    int gcol = gcol0 + m;
    float bb = b1[gcol];
    #pragma unroll
    for (int reg = 0; reg < 4; ++reg) {
        int row = quad * 4 + reg;
        h1f[(row0 + row) * 256 + gcol] = f2fp8(fmaxf(acc[reg] + bb, 0.f) * s_out[row]);
    }
}

// ---------------- layer2: agg (16 waves, 1 dst/wave) + MFMA GEMM (+ labels), fused ----
__global__ void layer2_kernel(const int* __restrict__ off1, const int* __restrict__ esrc1,
                              const unsigned char* __restrict__ h1f,
                              const unsigned short* __restrict__ W2Tb,
                              const float* __restrict__ b2,
                              const int* __restrict__ labels,
                              float* __restrict__ out) {
    __shared__ unsigned short A[16 * 264];   // bf16 rows of 256, stride 264 (528B)
    int t = threadIdx.x;
    int row0 = blockIdx.x * 16;
    int w = t >> 6, lane = t & 63;
    // ---- agg phase: wave w -> dst row0 + w (64 lanes x uint = 256 fp8 row) ----
    {
        int d = row0 + w;
        f32x2 a01 = {0.f, 0.f}, a23 = {0.f, 0.f};
        float sc = 0.f;
        if (d < NDST1) {
            int lo = off1[d], hi = off1[d + 1];
            const unsigned* h4 = (const unsigned*)h1f;     // row = 64 uints
            int j = lo;
            for (; j + 3 < hi; j += 4) {                   // 4 loads in flight
                unsigned v0 = h4[esrc1[j] * 64 + lane];
                unsigned v1 = h4[esrc1[j + 1] * 64 + lane];
                unsigned v2 = h4[esrc1[j + 2] * 64 + lane];
                unsigned v3 = h4[esrc1[j + 3] * 64 + lane];
                a01 += up_lo(v0) + up_lo(v1) + up_lo(v2) + up_lo(v3);
                a23 += up_hi(v0) + up_hi(v1) + up_hi(v2) + up_hi(v3);
            }
            for (; j < hi; ++j) {
                unsigned v = h4[esrc1[j] * 64 + lane];
                a01 += up_lo(v); a23 += up_hi(v);
            }
            sc = rsqrtf(fmaxf((float)(hi - lo), 1.0f)) * (1.0f / H1S);
        }
        uint2 o; o.x = pack2(a01.x * sc, a01.y * sc); o.y = pack2(a23.x * sc, a23.y * sc);
        *(uint2*)(A + w * 264 + lane * 4) = o;
    }
    __syncthreads();
    if (w == 0) {                        // ---- gemm phase: single 16x16 tile ----
        int m = lane & 15, quad = lane >> 4;
        const unsigned short* bbase = W2Tb + m * 256 + quad * 8;
        f32x4 acc = {0.f, 0.f, 0.f, 0.f};
        #pragma unroll
        for (int ks = 0; ks < 8; ++ks) {
            bf16x8 af = *(const bf16x8*)(A + m * 264 + quad * 8 + ks * 32);
            bf16x8 bf = *(const bf16x8*)(bbase + ks * 32);
            acc = __builtin_amdgcn_mfma_f32_16x16x32_bf16(af, bf, acc, 0, 0, 0);
        }
        float bb = b2[m];
        #pragma unroll
        for (int reg = 0; reg < 4; ++reg) {
            int row = row0 + quad * 4 + reg;
            if (row < NDST1)
                out[row * NOUT + m] = fmaxf(acc[reg] + bb, 0.f);
        }
        if (lane < 16 && row0 + lane < NDST1)
            out[NDST1 * NOUT + row0 + lane] = (float)labels[row0 + lane];
    }
}

extern "C" void kernel_launch(void* const* d_in, const int* in_sizes, int n_in,
                              void* d_out, int out_size, void* d_ws, size_t ws_size,
                              hipStream_t stream) {
    const int*   user_word  = (const int*)d_in[0];
    const int*   labels     = (const int*)d_in[1];
    const int*   src0       = (const int*)d_in[2];
    const int*   dst0       = (const int*)d_in[3];
    const int*   src1       = (const int*)d_in[4];
    const int*   dst1       = (const int*)d_in[5];
    const float* word_table = (const float*)d_in[6];
    const float* W1         = (const float*)d_in[7];
    const float* b1         = (const float*)d_in[8];
    const float* W2         = (const float*)d_in[9];
    const float* b2         = (const float*)d_in[10];

    int* iws = (int*)d_ws;
    int* cnt0  = iws;            // 20000  ┐
    int* cnt1  = iws + 20000;    //  5000  │ zeroed (95000 ints)
    int* degO0 = iws + 25000;    // 50000  │
    int* degO1 = iws + 75000;    // 20000  ┘
    int* off0  = iws + 95000;    // 20001
    int* off1  = iws + 115001;   //  5001
    int* cur0  = iws + 120002;   // 20000
    int* cur1  = iws + 140002;   //  5000
    int* esrc0 = iws + 145002;   // 300000
    int* esrc1 = iws + 445002;   // 75000   (end 520002; pad to 520004)
    unsigned char*  wt8  = (unsigned char*)(iws + 520004);   // 6.4M fp8  = 1.6M ints
    unsigned char*  x0f  = (unsigned char*)(iws + 2120004);  // 6.4M fp8  = 1.6M ints
    unsigned char*  h1f  = (unsigned char*)(iws + 3720004);  // 5.12M fp8 = 1.28M ints
    unsigned short* W1Tb = (unsigned short*)(iws + 5000004); // 32768 bf16 = 8192 ints
    unsigned short* W2Tb = (unsigned short*)(iws + 5008196); // 4096 bf16 (end ≈ 20 MB)

    hipMemsetAsync(iws, 0, 95000 * sizeof(int), stream);

    prep_kernel<<<(NSRC0 * EMB / 8 + 255) / 256, 256, 0, stream>>>(
        word_table, wt8, W1, W1Tb, W2, W2Tb,
        src0, dst0, src1, dst1, cnt0, cnt1, degO0, degO1);
    scan_kernel<<<2, 1024, 0, stream>>>(cnt0, off0, cur0, cnt1, off1, cur1);
    embed_bucket_kernel<<<NEMB_BLK * 2, 256, 0, stream>>>(
        user_word, wt8, degO0, x0f,
        src0, dst0, src1, dst1, cur0, cur1, esrc0, esrc1);
    layer1_kernel<<<NDST0 / 16, 1024, 0, stream>>>(off0, esrc0, x0f, degO1, W1Tb, b1, h1f);
    layer2_kernel<<<(NDST1 + 15) / 16, 1024, 0, stream>>>(off1, esrc1, h1f, W2Tb, b2,
                                                          labels, (float*)d_out);
}

// Round 4
// 255.013 us; speedup vs baseline: 1.0306x; 1.0141x over previous
//
#include <hip/hip_runtime.h>

#define E0     300000
#define E1     75000
#define NSRC0  50000
#define NDST0  20000
#define NDST1  5000
#define EMB    128
#define HID    256
#define NOUT   16

#define NPB        40     // nodes per embed block (1250 * 40 = 50000 exactly)
#define TILE_SHIFT 12     // 4096-row vocab tiles; tiles 0..12
#define NEMB_BLK   (NSRC0 / NPB)          // 1250

#define X0S  32.0f        // fp8 pre-scale for x0  (undone in layer1 agg)
#define H1S  64.0f        // fp8 pre-scale for h1  (undone in layer2 agg)

typedef __attribute__((ext_vector_type(8))) short bf16x8;   // MFMA A/B frag (4 VGPRs)
typedef __attribute__((ext_vector_type(4))) float f32x4;    // MFMA C/D frag
typedef __attribute__((ext_vector_type(2))) float f32x2;

// ---- bf16 helpers ----
__device__ __forceinline__ unsigned short f2bf(float f) {
    unsigned u = __float_as_uint(f);
    return (unsigned short)((u + 0x7FFFu + ((u >> 16) & 1u)) >> 16);
}
__device__ __forceinline__ unsigned pack2(float a, float b) {
    return (unsigned)f2bf(a) | ((unsigned)f2bf(b) << 16);
}
// ---- fp8 e4m3 helpers (HW cvt) ----
__device__ __forceinline__ unsigned pack4_fp8(float a0, float a1, float a2, float a3) {
    unsigned p = 0;
    p = __builtin_amdgcn_cvt_pk_fp8_f32(a0, a1, p, false);   // bytes 0,1
    p = __builtin_amdgcn_cvt_pk_fp8_f32(a2, a3, p, true);    // bytes 2,3
    return p;
}
__device__ __forceinline__ unsigned char f2fp8(float v) {
    unsigned p = __builtin_amdgcn_cvt_pk_fp8_f32(v, v, 0, false);
    return (unsigned char)(p & 0xFF);
}
// unpack 4 fp8 bytes -> two float2 (packed HW cvt when available)
#if __has_builtin(__builtin_amdgcn_cvt_pk_f32_fp8)
__device__ __forceinline__ f32x2 up_lo(unsigned v) { return __builtin_amdgcn_cvt_pk_f32_fp8(v, false); }
__device__ __forceinline__ f32x2 up_hi(unsigned v) { return __builtin_amdgcn_cvt_pk_f32_fp8(v, true); }
#else
__device__ __forceinline__ f32x2 up_lo(unsigned v) {
    f32x2 r; r.x = __builtin_amdgcn_cvt_f32_fp8(v, 0); r.y = __builtin_amdgcn_cvt_f32_fp8(v, 1); return r;
}
__device__ __forceinline__ f32x2 up_hi(unsigned v) {
    f32x2 r; r.x = __builtin_amdgcn_cvt_f32_fp8(v, 2); r.y = __builtin_amdgcn_cvt_f32_fp8(v, 3); return r;
}
#endif

// ---------------- prep: table->fp8, W1^T/W2^T->bf16, degree histograms ----------------
__global__ void prep_kernel(const float* __restrict__ wt, unsigned char* __restrict__ wt8,
                            const float* __restrict__ W1, unsigned short* __restrict__ W1Tb,
                            const float* __restrict__ W2, unsigned short* __restrict__ W2Tb,
                            const int* __restrict__ src0, const int* __restrict__ dst0,
                            const int* __restrict__ src1, const int* __restrict__ dst1,
                            int* cnt0, int* cnt1, int* degO0, int* degO1) {
    int i = blockIdx.x * blockDim.x + threadIdx.x;
    if (i < NSRC0 * EMB / 8) {            // 800000: pack 8 floats -> 8 fp8
        const float4* in = (const float4*)wt;
        float4 v0 = in[i * 2], v1 = in[i * 2 + 1];
        uint2 o;
        o.x = pack4_fp8(v0.x, v0.y, v0.z, v0.w);
        o.y = pack4_fp8(v1.x, v1.y, v1.z, v1.w);
        ((uint2*)wt8)[i] = o;
    }
    if (i < EMB * HID) {                  // W1[128][256] -> W1T bf16 [256][128]
        int n = i & 255, k = i >> 8;
        W1Tb[n * 128 + k] = f2bf(W1[i]);
    }
    if (i < HID * NOUT) {                 // W2[256][16] -> W2T bf16 [16][256]
        int n = i & 15, k = i >> 4;
        W2Tb[n * 256 + k] = f2bf(W2[i]);
    }
    if (i < E0) {
        atomicAdd(&cnt0[dst0[i]], 1);
        atomicAdd(&degO0[src0[i]], 1);
    }
    if (i < E1) {
        atomicAdd(&cnt1[dst1[i]], 1);
        atomicAdd(&degO1[src1[i]], 1);
    }
}

// ---------------- exclusive scan (2 blocks x 1024 threads, own dispatch) --------------
__device__ void scan_body(const int* __restrict__ cnt, int n,
                          int* __restrict__ off, int* __restrict__ cur) {
    __shared__ int sums[1024];
    int t = threadIdx.x;
    int chunk = (n + 1023) / 1024;
    int lo = t * chunk, hi = min(lo + chunk, n);
    int s = 0;
    for (int i = lo; i < hi; ++i) s += cnt[i];
    sums[t] = s;
    __syncthreads();
    for (int d = 1; d < 1024; d <<= 1) {
        int x = (t >= d) ? sums[t - d] : 0;
        __syncthreads();
        sums[t] += x;
        __syncthreads();
    }
    int run = (t == 0) ? 0 : sums[t - 1];
    for (int i = lo; i < hi; ++i) {
        off[i] = run; cur[i] = run;
        run += cnt[i];
    }
    if (t == 1023) off[n] = run;
}

__global__ void scan_kernel(const int* cnt0, int* off0, int* cur0,
                            const int* cnt1, int* off1, int* cur1) {
    if (blockIdx.x == 0) scan_body(cnt0, NDST0, off0, cur0);
    else                 scan_body(cnt1, NDST1, off1, cur1);
}

// ---------------- embed (even blocks) + edge bucket (odd blocks), interleaved ---------
// Staging: user_word -> LDS coalesced int4 (direct per-node reads cost +33MB HBM, r1).
// Sort: wave-parallel ballot counting-sort, 13 tile buckets, conflict-free (r1).
// Gather: uint per lane (32 lanes = one full 128B row per instruction).
// MLP depth vs L2 locality (r0-r3 sweep): 10 streams = 57MB fetch / 70us (latency-
// bound); 20 streams = 98MB / 68us (LLC-BW-bound). 15 streams targets the knee.
__global__ void embed_bucket_kernel(const int* __restrict__ user_word,
                                    const unsigned char* __restrict__ wt8,
                                    const int* __restrict__ degO0,
                                    unsigned char* __restrict__ x0f,
                                    const int* __restrict__ src0, const int* __restrict__ dst0,
                                    const int* __restrict__ src1, const int* __restrict__ dst1,
                                    int* cur0, int* cur1, int* esrc0, int* esrc1) {
    if (blockIdx.x & 1) {                // ---- bucket part (odd blocks) ----
        int i = (blockIdx.x >> 1) * 256 + threadIdx.x;
        if (i < E0) {
            int p = atomicAdd(&cur0[dst0[i]], 1);
            esrc0[p] = src0[i];
        }
        if (i < E1) {
            int p = atomicAdd(&cur1[dst1[i]], 1);
            esrc1[p] = src1[i];
        }
        return;
    }
    // ---- embed part (even blocks) ----
    int eb = blockIdx.x >> 1;            // 0..1249
    __shared__ int raw[NPB * 50];                // 8000 B, coalesced stage
    __shared__ unsigned short srt[NPB * 50];     // 4000 B, tile-sorted word ids
    int t = threadIdx.x;
    {   // int4-coalesced stage: 500 int4 = 2000 ints (base is 16B-aligned: eb*8000B)
        const int4* uw4 = (const int4*)(user_word + eb * NPB * 50);
        int4* raw4 = (int4*)raw;
        for (int j = t; j < NPB * 50 / 4; j += 256)
            raw4[j] = uw4[j];
    }
    __syncthreads();
    {   // ---- wave-parallel tile sort: wave wv sorts nodes wv, wv+4, ..., wv+36 ----
        int wv = t >> 6, j = t & 63;
        unsigned long long lmlt = (1ULL << j) - 1;       // lanes strictly below j
        for (int n = wv; n < NPB; n += 4) {
            int word = 0, b = 16;                        // j>=50 lanes: bucket 16 (inert)
            if (j < 50) { word = raw[n * 50 + j]; b = word >> TILE_SHIFT; }
            int pos = 0;
            #pragma unroll
            for (int bb = 0; bb < 13; ++bb) {
                unsigned long long m = __ballot(b == bb);
                if (bb < b)       pos += __popcll(m);
                else if (bb == b) pos += __popcll(m & lmlt);
            }
            if (j < 50) srt[n * 50 + pos] = (unsigned short)word;
        }
    }
    __syncthreads();
    int g = t >> 5, l = t & 31;                   // 8 groups of 32 lanes
    const unsigned* wt4 = (const unsigned*)wt8;   // row = 32 uints
    const unsigned short* id[5];
    #pragma unroll
    for (int k = 0; k < 5; ++k) id[k] = srt + (g + 8 * k) * 50;
    f32x2 a01[5], a23[5];
    #pragma unroll
    for (int k = 0; k < 5; ++k) { a01[k] = (f32x2){0.f, 0.f}; a23[k] = (f32x2){0.f, 0.f}; }
    int j = 0;
    for (; j + 2 < 50; j += 3) {                  // 3 positions x 5 nodes = 15 in flight
        unsigned v[5][3];
        #pragma unroll
        for (int k = 0; k < 5; ++k)
            #pragma unroll
            for (int u = 0; u < 3; ++u)
                v[k][u] = wt4[(int)id[k][j + u] * 32 + l];
        #pragma unroll
        for (int k = 0; k < 5; ++k)
            #pragma unroll
            for (int u = 0; u < 3; ++u) {
                a01[k] += up_lo(v[k][u]); a23[k] += up_hi(v[k][u]);
            }
    }
    {   // tail: positions 48,49
        unsigned v[5][2];
        #pragma unroll
        for (int k = 0; k < 5; ++k)
            #pragma unroll
            for (int u = 0; u < 2; ++u)
                v[k][u] = wt4[(int)id[k][48 + u] * 32 + l];
        #pragma unroll
        for (int k = 0; k < 5; ++k)
            #pragma unroll
            for (int u = 0; u < 2; ++u) {
                a01[k] += up_lo(v[k][u]); a23[k] += up_hi(v[k][u]);
            }
    }
    #pragma unroll
    for (int k = 0; k < 5; ++k) {
        int node = eb * NPB + g + k * 8;
        float s = rsqrtf(fmaxf((float)degO0[node], 1.0f)) * (0.02f * X0S); // 1/50 mean
        ((unsigned*)x0f)[node * 32 + l] =
            pack4_fp8(a01[k].x * s, a01[k].y * s, a23[k].x * s, a23[k].y * s);
    }
}

// ---------------- layer1: agg (16 waves, 1 dst/wave) + MFMA GEMM, fused --------------
// 1024 threads = 16 waves; wave w aggregates dst row0+w (full TLP: 20000 waves total,
// same as standalone agg1 -- r8's failure was 4 waves x 4 serial rows). Agg loop is
// 8-edge unrolled: 4 outstanding 128B loads per half-wave (was 2; same latency lever
// as embed). LDS A-tile [16][136] bf16 (pad 8 -> b128 reads 2-way-aliased = free).
// After one barrier, wave w computes col-tile w (16 cols) of 16x256 out via 4 MFMA.
__global__ void layer1_kernel(const int* __restrict__ off0, const int* __restrict__ esrc0,
                              const unsigned char* __restrict__ x0f,
                              const int* __restrict__ degO1,
                              const unsigned short* __restrict__ W1Tb,
                              const float* __restrict__ b1,
                              unsigned char* __restrict__ h1f) {
    __shared__ unsigned short A[16 * 136];   // bf16, stride 136 (272B)
    __shared__ float s_out[16];
    int t = threadIdx.x;
    int row0 = blockIdx.x * 16;
    int w = t >> 6, lane = t & 63;
    int half = lane >> 5, l = lane & 31;
    if (t < 16) s_out[t] = rsqrtf(fmaxf((float)degO1[row0 + t], 1.0f)) * H1S;
    // ---- agg phase: wave w -> dst row0 + w ----
    {
        int d = row0 + w;
        int lo = off0[d], hi = off0[d + 1];
        const unsigned* x4 = (const unsigned*)x0f;     // row = 32 uints
        f32x2 a01a = {0.f, 0.f}, a23a = {0.f, 0.f};
        f32x2 a01b = {0.f, 0.f}, a23b = {0.f, 0.f};
        int j = lo + half;
        for (; j + 6 < hi; j += 8) {                   // 4 loads in flight/half-wave
            unsigned va = x4[esrc0[j] * 32 + l];
            unsigned vb = x4[esrc0[j + 2] * 32 + l];
            unsigned vc = x4[esrc0[j + 4] * 32 + l];
            unsigned vd = x4[esrc0[j + 6] * 32 + l];
            a01a += up_lo(va); a23a += up_hi(va);
            a01b += up_lo(vb); a23b += up_hi(vb);
            a01a += up_lo(vc); a23a += up_hi(vc);
            a01b += up_lo(vd); a23b += up_hi(vd);
        }
        for (; j + 2 < hi; j += 4) {
            unsigned va = x4[esrc0[j] * 32 + l];
            unsigned vb = x4[esrc0[j + 2] * 32 + l];
            a01a += up_lo(va); a23a += up_hi(va);
            a01b += up_lo(vb); a23b += up_hi(vb);
        }
        if (j < hi) {
            unsigned v = x4[esrc0[j] * 32 + l];
            a01a += up_lo(v); a23a += up_hi(v);
        }
        f32x2 a01 = a01a + a01b, a23 = a23a + a23b;
        a01.x += __shfl_down(a01.x, 32); a01.y += __shfl_down(a01.y, 32);
        a23.x += __shfl_down(a23.x, 32); a23.y += __shfl_down(a23.y, 32);
        if (half == 0) {
            float sc = rsqrtf(fmaxf((float)(hi - lo), 1.0f)) * (1.0f / X0S);
            uint2 o; o.x = pack2(a01.x * sc, a01.y * sc); o.y = pack2(a23.x * sc, a23.y * sc);
            *(uint2*)(A + w * 136 + l * 4) = o;        // 4 bf16 per lane
        }
    }
    __syncthreads();
    // ---- gemm phase: wave w -> col tile w (cols 16w..16w+15) ----
    int m = lane & 15, quad = lane >> 4;
    bf16x8 afr[4];
    #pragma unroll
    for (int ks = 0; ks < 4; ++ks)
        afr[ks] = *(const bf16x8*)(A + m * 136 + quad * 8 + ks * 32);
    int gcol0 = w * 16;
    const unsigned short* bbase = W1Tb + (gcol0 + m) * 128 + quad * 8;
    f32x4 acc = {0.f, 0.f, 0.f, 0.f};
    #pragma unroll
    for (int ks = 0; ks < 4; ++ks) {
        bf16x8 bfr = *(const bf16x8*)(bbase + ks * 32);
        acc = __builtin_amdgcn_mfma_f32_16x16x32_bf16(afr[ks], bfr, acc, 0, 0, 0);
    }
    int gcol = gcol0 + m;
    float bb = b1[gcol];
    #pragma unroll
    for (int reg = 0; reg < 4; ++reg) {
        int row = quad * 4 + reg;
        h1f[(row0 + row) * 256 + gcol] = f2fp8(fmaxf(acc[reg] + bb, 0.f) * s_out[row]);
    }
}

// ---------------- layer2: agg (16 waves, 1 dst/wave) + MFMA GEMM (+ labels), fused ----
__global__ void layer2_kernel(const int* __restrict__ off1, const int* __restrict__ esrc1,
                              const unsigned char* __restrict__ h1f,
                              const unsigned short* __restrict__ W2Tb,
                              const float* __restrict__ b2,
                              const int* __restrict__ labels,
                              float* __restrict__ out) {
    __shared__ unsigned short A[16 * 264];   // bf16 rows of 256, stride 264 (528B)
    int t = threadIdx.x;
    int row0 = blockIdx.x * 16;
    int w = t >> 6, lane = t & 63;
    // ---- agg phase: wave w -> dst row0 + w (64 lanes x uint = 256 fp8 row) ----
    {
        int d = row0 + w;
        f32x2 a01 = {0.f, 0.f}, a23 = {0.f, 0.f};
        float sc = 0.f;
        if (d < NDST1) {
            int lo = off1[d], hi = off1[d + 1];
            const unsigned* h4 = (const unsigned*)h1f;     // row = 64 uints
            int j = lo;
            for (; j + 3 < hi; j += 4) {                   // 4 loads in flight
                unsigned v0 = h4[esrc1[j] * 64 + lane];
                unsigned v1 = h4[esrc1[j + 1] * 64 + lane];
                unsigned v2 = h4[esrc1[j + 2] * 64 + lane];
                unsigned v3 = h4[esrc1[j + 3] * 64 + lane];
                a01 += up_lo(v0) + up_lo(v1) + up_lo(v2) + up_lo(v3);
                a23 += up_hi(v0) + up_hi(v1) + up_hi(v2) + up_hi(v3);
            }
            for (; j < hi; ++j) {
                unsigned v = h4[esrc1[j] * 64 + lane];
                a01 += up_lo(v); a23 += up_hi(v);
            }
            sc = rsqrtf(fmaxf((float)(hi - lo), 1.0f)) * (1.0f / H1S);
        }
        uint2 o; o.x = pack2(a01.x * sc, a01.y * sc); o.y = pack2(a23.x * sc, a23.y * sc);
        *(uint2*)(A + w * 264 + lane * 4) = o;
    }
    __syncthreads();
    if (w == 0) {                        // ---- gemm phase: single 16x16 tile ----
        int m = lane & 15, quad = lane >> 4;
        const unsigned short* bbase = W2Tb + m * 256 + quad * 8;
        f32x4 acc = {0.f, 0.f, 0.f, 0.f};
        #pragma unroll
        for (int ks = 0; ks < 8; ++ks) {
            bf16x8 af = *(const bf16x8*)(A + m * 264 + quad * 8 + ks * 32);
            bf16x8 bf = *(const bf16x8*)(bbase + ks * 32);
            acc = __builtin_amdgcn_mfma_f32_16x16x32_bf16(af, bf, acc, 0, 0, 0);
        }
        float bb = b2[m];
        #pragma unroll
        for (int reg = 0; reg < 4; ++reg) {
            int row = row0 + quad * 4 + reg;
            if (row < NDST1)
                out[row * NOUT + m] = fmaxf(acc[reg] + bb, 0.f);
        }
        if (lane < 16 && row0 + lane < NDST1)
            out[NDST1 * NOUT + row0 + lane] = (float)labels[row0 + lane];
    }
}

extern "C" void kernel_launch(void* const* d_in, const int* in_sizes, int n_in,
                              void* d_out, int out_size, void* d_ws, size_t ws_size,
                              hipStream_t stream) {
    const int*   user_word  = (const int*)d_in[0];
    const int*   labels     = (const int*)d_in[1];
    const int*   src0       = (const int*)d_in[2];
    const int*   dst0       = (const int*)d_in[3];
    const int*   src1       = (const int*)d_in[4];
    const int*   dst1       = (const int*)d_in[5];
    const float* word_table = (const float*)d_in[6];
    const float* W1         = (const float*)d_in[7];
    const float* b1         = (const float*)d_in[8];
    const float* W2         = (const float*)d_in[9];
    const float* b2         = (const float*)d_in[10];

    int* iws = (int*)d_ws;
    int* cnt0  = iws;            // 20000  ┐
    int* cnt1  = iws + 20000;    //  5000  │ zeroed (95000 ints)
    int* degO0 = iws + 25000;    // 50000  │
    int* degO1 = iws + 75000;    // 20000  ┘
    int* off0  = iws + 95000;    // 20001
    int* off1  = iws + 115001;   //  5001
    int* cur0  = iws + 120002;   // 20000
    int* cur1  = iws + 140002;   //  5000
    int* esrc0 = iws + 145002;   // 300000
    int* esrc1 = iws + 445002;   // 75000   (end 520002; pad to 520004)
    unsigned char*  wt8  = (unsigned char*)(iws + 520004);   // 6.4M fp8  = 1.6M ints
    unsigned char*  x0f  = (unsigned char*)(iws + 2120004);  // 6.4M fp8  = 1.6M ints
    unsigned char*  h1f  = (unsigned char*)(iws + 3720004);  // 5.12M fp8 = 1.28M ints
    unsigned short* W1Tb = (unsigned short*)(iws + 5000004); // 32768 bf16 = 8192 ints
    unsigned short* W2Tb = (unsigned short*)(iws + 5008196); // 4096 bf16 (end ≈ 20 MB)

    hipMemsetAsync(iws, 0, 95000 * sizeof(int), stream);

    prep_kernel<<<(NSRC0 * EMB / 8 + 255) / 256, 256, 0, stream>>>(
        word_table, wt8, W1, W1Tb, W2, W2Tb,
        src0, dst0, src1, dst1, cnt0, cnt1, degO0, degO1);
    scan_kernel<<<2, 1024, 0, stream>>>(cnt0, off0, cur0, cnt1, off1, cur1);
    embed_bucket_kernel<<<NEMB_BLK * 2, 256, 0, stream>>>(
        user_word, wt8, degO0, x0f,
        src0, dst0, src1, dst1, cur0, cur1, esrc0, esrc1);
    layer1_kernel<<<NDST0 / 16, 1024, 0, stream>>>(off0, esrc0, x0f, degO1, W1Tb, b1, h1f);
    layer2_kernel<<<(NDST1 + 15) / 16, 1024, 0, stream>>>(off1, esrc1, h1f, W2Tb, b2,
                                                          labels, (float*)d_out);
}

// Round 6
// 247.834 us; speedup vs baseline: 1.0604x; 1.0290x over previous
//
#include <hip/hip_runtime.h>

#define E0     300000
#define E1     75000
#define NSRC0  50000
#define NDST0  20000
#define NDST1  5000
#define EMB    128
#define HID    256
#define NOUT   16

#define NPB        40     // nodes per embed block-pair (1250 * 40 = 50000 exactly)
#define TILE_SHIFT 12     // 4096-row vocab tiles; tiles 0..12
#define NEB2       2504   // embed half-blocks: eb = (bi>>3)*4 + (bi&3), half = (bi>>2)&1
#define E0S        120    // E0 edges bucketed per block (120*2504 >= 300000)
#define E1S        30     // E1 edges bucketed per block (30*2504 >= 75000)

#define X0S  32.0f        // fp8 pre-scale for x0  (undone in layer1 agg)
#define H1S  64.0f        // fp8 pre-scale for h1  (undone in layer2 agg)

typedef __attribute__((ext_vector_type(8))) short bf16x8;   // MFMA A/B frag (4 VGPRs)
typedef __attribute__((ext_vector_type(4))) float f32x4;    // MFMA C/D frag
typedef __attribute__((ext_vector_type(2))) float f32x2;

// ---- bf16 helpers ----
__device__ __forceinline__ unsigned short f2bf(float f) {
    unsigned u = __float_as_uint(f);
    return (unsigned short)((u + 0x7FFFu + ((u >> 16) & 1u)) >> 16);
}
__device__ __forceinline__ unsigned pack2(float a, float b) {
    return (unsigned)f2bf(a) | ((unsigned)f2bf(b) << 16);
}
// ---- fp8 e4m3 helpers (HW cvt) ----
__device__ __forceinline__ unsigned pack4_fp8(float a0, float a1, float a2, float a3) {
    unsigned p = 0;
    p = __builtin_amdgcn_cvt_pk_fp8_f32(a0, a1, p, false);   // bytes 0,1
    p = __builtin_amdgcn_cvt_pk_fp8_f32(a2, a3, p, true);    // bytes 2,3
    return p;
}
__device__ __forceinline__ unsigned char f2fp8(float v) {
    unsigned p = __builtin_amdgcn_cvt_pk_fp8_f32(v, v, 0, false);
    return (unsigned char)(p & 0xFF);
}
// unpack 4 fp8 bytes -> two float2 (packed HW cvt when available)
#if __has_builtin(__builtin_amdgcn_cvt_pk_f32_fp8)
__device__ __forceinline__ f32x2 up_lo(unsigned v) { return __builtin_amdgcn_cvt_pk_f32_fp8(v, false); }
__device__ __forceinline__ f32x2 up_hi(unsigned v) { return __builtin_amdgcn_cvt_pk_f32_fp8(v, true); }
#else
__device__ __forceinline__ f32x2 up_lo(unsigned v) {
    f32x2 r; r.x = __builtin_amdgcn_cvt_f32_fp8(v, 0); r.y = __builtin_amdgcn_cvt_f32_fp8(v, 1); return r;
}
__device__ __forceinline__ f32x2 up_hi(unsigned v) {
    f32x2 r; r.x = __builtin_amdgcn_cvt_f32_fp8(v, 2); r.y = __builtin_amdgcn_cvt_f32_fp8(v, 3); return r;
}
#endif

// ---------------- prep: table->fp8 planes, W1^T/W2^T->bf16, degree histograms --------
// wt8 stored as two column-planes: plane p = cols [p*64, p*64+64) of all rows,
// 3.2 MB each (fits a 4MB per-XCD L2; full 6.4MB table does not -- r4 fetch=93MB).
__global__ void prep_kernel(const float* __restrict__ wt, unsigned char* __restrict__ wt8,
                            const float* __restrict__ W1, unsigned short* __restrict__ W1Tb,
                            const float* __restrict__ W2, unsigned short* __restrict__ W2Tb,
                            const int* __restrict__ src0, const int* __restrict__ dst0,
                            const int* __restrict__ src1, const int* __restrict__ dst1,
                            int* cnt0, int* cnt1, int* degO0, int* degO1) {
    int i = blockIdx.x * blockDim.x + threadIdx.x;
    if (i < NSRC0 * EMB / 8) {            // 800000: pack 8 floats -> 8 fp8
        const float4* in = (const float4*)wt;
        float4 v0 = in[i * 2], v1 = in[i * 2 + 1];
        uint2 o;
        o.x = pack4_fp8(v0.x, v0.y, v0.z, v0.w);
        o.y = pack4_fp8(v1.x, v1.y, v1.z, v1.w);
        int row = i >> 4, q = i & 15;     // q = 8-byte group within 128B row
        ((uint2*)wt8)[(q >> 3) * 400000 + row * 8 + (q & 7)] = o;   // plane split
    }
    if (i < EMB * HID) {                  // W1[128][256] -> W1T bf16 [256][128]
        int n = i & 255, k = i >> 8;
        W1Tb[n * 128 + k] = f2bf(W1[i]);
    }
    if (i < HID * NOUT) {                 // W2[256][16] -> W2T bf16 [16][256]
        int n = i & 15, k = i >> 4;
        W2Tb[n * 256 + k] = f2bf(W2[i]);
    }
    if (i < E0) {
        atomicAdd(&cnt0[dst0[i]], 1);
        atomicAdd(&degO0[src0[i]], 1);
    }
    if (i < E1) {
        atomicAdd(&cnt1[dst1[i]], 1);
        atomicAdd(&degO1[src1[i]], 1);
    }
}

// ---------------- exclusive scan (2 blocks x 1024 threads, own dispatch) --------------
__device__ void scan_body(const int* __restrict__ cnt, int n,
                          int* __restrict__ off, int* __restrict__ cur) {
    __shared__ int sums[1024];
    int t = threadIdx.x;
    int chunk = (n + 1023) / 1024;
    int lo = t * chunk, hi = min(lo + chunk, n);
    int s = 0;
    for (int i = lo; i < hi; ++i) s += cnt[i];
    sums[t] = s;
    __syncthreads();
    for (int d = 1; d < 1024; d <<= 1) {
        int x = (t >= d) ? sums[t - d] : 0;
        __syncthreads();
        sums[t] += x;
        __syncthreads();
    }
    int run = (t == 0) ? 0 : sums[t - 1];
    for (int i = lo; i < hi; ++i) {
        off[i] = run; cur[i] = run;
        run += cnt[i];
    }
    if (t == 1023) off[n] = run;
}

__global__ void scan_kernel(const int* cnt0, int* off0, int* cur0,
                            const int* cnt1, int* off1, int* cur1) {
    if (blockIdx.x == 0) scan_body(cnt0, NDST0, off0, cur0);
    else                 scan_body(cnt1, NDST1, off1, cur1);
}

// ---------------- embed + bucket, fused into EVERY block ------------------------------
// r0-r4 lesson: the old even=embed/odd=bucket split starved embed to half the XCDs
// (round-robin blockIdx%8 -> even blocks land on even XCDs only); VALUBusy/occupancy
// were pinned at ~36/42% for 4 rounds. Now every block does a 120+30 edge bucket slice
// (no barrier; overlaps with staging) then an embed HALF-tile:
//   eb = (bi>>3)*4 + (bi&3), half = (bi>>2)&1  -> XCDs 0-3 read plane 0 (3.2MB,
// L2-resident), XCDs 4-7 plane 1. Gather: 16 lanes = one 64B half-row; 32-lane group
// covers 2 sorted positions/instr; 3 pairs x 5 nodes = 15 loads in flight per group.
__global__ void embed_bucket_kernel(const int* __restrict__ user_word,
                                    const unsigned char* __restrict__ wt8,
                                    const int* __restrict__ degO0,
                                    unsigned char* __restrict__ x0f,
                                    const int* __restrict__ src0, const int* __restrict__ dst0,
                                    const int* __restrict__ src1, const int* __restrict__ dst1,
                                    int* cur0, int* cur1, int* esrc0, int* esrc1) {
    int bi = blockIdx.x;
    int t = threadIdx.x;
    // ---- bucket slice (all blocks; latency overlaps the stage/sort below) ----
    if (t < E0S) {
        int i = bi * E0S + t;
        if (i < E0) { int p = atomicAdd(&cur0[dst0[i]], 1); esrc0[p] = src0[i]; }
    } else if (t < E0S + E1S) {
        int i = bi * E1S + (t - E0S);
        if (i < E1) { int p = atomicAdd(&cur1[dst1[i]], 1); esrc1[p] = src1[i]; }
    }
    // ---- embed half-tile ----
    int eb = (bi >> 3) * 4 + (bi & 3);   // node-group 0..1251 (>=1250 idle)
    int half = (bi >> 2) & 1;            // column plane
    if (eb >= NSRC0 / NPB) return;
    __shared__ int raw[NPB * 50];                // 8000 B, coalesced stage
    __shared__ unsigned short srt[NPB * 50];     // 4000 B, tile-sorted word ids
    {   // int4-coalesced stage: 500 int4 (base 16B-aligned: eb*8000B)
        const int4* uw4 = (const int4*)(user_word + eb * NPB * 50);
        int4* raw4 = (int4*)raw;
        for (int j = t; j < NPB * 50 / 4; j += 256)
            raw4[j] = uw4[j];
    }
    __syncthreads();
    {   // ---- wave-parallel tile sort: wave wv sorts nodes wv, wv+4, ..., wv+36 ----
        int wv = t >> 6, j = t & 63;
        unsigned long long lmlt = (1ULL << j) - 1;       // lanes strictly below j
        for (int n = wv; n < NPB; n += 4) {
            int word = 0, b = 16;                        // j>=50 lanes: bucket 16 (inert)
            if (j < 50) { word = raw[n * 50 + j]; b = word >> TILE_SHIFT; }
            int pos = 0;
            #pragma unroll
            for (int bb = 0; bb < 13; ++bb) {
                unsigned long long m = __ballot(b == bb);
                if (bb < b)       pos += __popcll(m);
                else if (bb == b) pos += __popcll(m & lmlt);
            }
            if (j < 50) srt[n * 50 + pos] = (unsigned short)word;
        }
    }
    __syncthreads();
    int g = t >> 5, l = t & 31;                   // 8 groups of 32 lanes
    int sub = l >> 4, c = l & 15;                 // position parity, uint col in half-row
    const unsigned* wtp = (const unsigned*)(wt8 + half * (NSRC0 * 64));  // row = 16 uints
    const unsigned short* id[5];
    #pragma unroll
    for (int k = 0; k < 5; ++k) id[k] = srt + (g + 8 * k) * 50;
    f32x2 alo[5], ahi[5];
    #pragma unroll
    for (int k = 0; k < 5; ++k) { alo[k] = (f32x2){0.f, 0.f}; ahi[k] = (f32x2){0.f, 0.f}; }
    int j = 0;
    for (; j + 5 < 50; j += 6) {                  // 3 pairs x 5 nodes = 15 in flight
        unsigned v[5][3];
        #pragma unroll
        for (int k = 0; k < 5; ++k)
            #pragma unroll
            for (int p = 0; p < 3; ++p)
                v[k][p] = wtp[(int)id[k][j + 2 * p + sub] * 16 + c];
        #pragma unroll
        for (int k = 0; k < 5; ++k)
            #pragma unroll
            for (int p = 0; p < 3; ++p) {
                alo[k] += up_lo(v[k][p]); ahi[k] += up_hi(v[k][p]);
            }
    }
    {   // tail pair: positions 48,49
        unsigned v[5];
        #pragma unroll
        for (int k = 0; k < 5; ++k) v[k] = wtp[(int)id[k][48 + sub] * 16 + c];
        #pragma unroll
        for (int k = 0; k < 5; ++k) { alo[k] += up_lo(v[k]); ahi[k] += up_hi(v[k]); }
    }
    // merge even/odd-position halves (lane <-> lane^16, stays within 32-group)
    #pragma unroll
    for (int k = 0; k < 5; ++k) {
        alo[k].x += __shfl_xor(alo[k].x, 16); alo[k].y += __shfl_xor(alo[k].y, 16);
        ahi[k].x += __shfl_xor(ahi[k].x, 16); ahi[k].y += __shfl_xor(ahi[k].y, 16);
    }
    if (sub == 0) {
        #pragma unroll
        for (int k = 0; k < 5; ++k) {
            int node = eb * NPB + g + 8 * k;
            float s = rsqrtf(fmaxf((float)degO0[node], 1.0f)) * (0.02f * X0S); // 1/50 mean
            ((unsigned*)x0f)[node * 32 + half * 16 + c] =
                pack4_fp8(alo[k].x * s, alo[k].y * s, ahi[k].x * s, ahi[k].y * s);
        }
    }
}

// ---------------- layer1: agg (16 waves, 1 dst/wave) + MFMA GEMM, fused --------------
// 1024 threads = 16 waves; wave w aggregates dst row0+w (full TLP: 20000 waves total).
// Agg loop 8-edge unrolled: 4 outstanding 128B loads per half-wave. LDS A-tile
// [16][136] bf16 (pad 8 -> b128 reads 2-way-aliased = free). After one barrier,
// wave w computes col-tile w (16 cols) of 16x256 out via 4 MFMA.
__global__ void layer1_kernel(const int* __restrict__ off0, const int* __restrict__ esrc0,
                              const unsigned char* __restrict__ x0f,
                              const int* __restrict__ degO1,
                              const unsigned short* __restrict__ W1Tb,
                              const float* __restrict__ b1,
                              unsigned char* __restrict__ h1f) {
    __shared__ unsigned short A[16 * 136];   // bf16, stride 136 (272B)
    __shared__ float s_out[16];
    int t = threadIdx.x;
    int row0 = blockIdx.x * 16;
    int w = t >> 6, lane = t & 63;
    int half = lane >> 5, l = lane & 31;
    if (t < 16) s_out[t] = rsqrtf(fmaxf((float)degO1[row0 + t], 1.0f)) * H1S;
    // ---- agg phase: wave w -> dst row0 + w ----
    {
        int d = row0 + w;
        int lo = off0[d], hi = off0[d + 1];
        const unsigned* x4 = (const unsigned*)x0f;     // row = 32 uints
        f32x2 a01a = {0.f, 0.f}, a23a = {0.f, 0.f};
        f32x2 a01b = {0.f, 0.f}, a23b = {0.f, 0.f};
        int j = lo + half;
        for (; j + 6 < hi; j += 8) {                   // 4 loads in flight/half-wave
            unsigned va = x4[esrc0[j] * 32 + l];
            unsigned vb = x4[esrc0[j + 2] * 32 + l];
            unsigned vc = x4[esrc0[j + 4] * 32 + l];
            unsigned vd = x4[esrc0[j + 6] * 32 + l];
            a01a += up_lo(va); a23a += up_hi(va);
            a01b += up_lo(vb); a23b += up_hi(vb);
            a01a += up_lo(vc); a23a += up_hi(vc);
            a01b += up_lo(vd); a23b += up_hi(vd);
        }
        for (; j + 2 < hi; j += 4) {
            unsigned va = x4[esrc0[j] * 32 + l];
            unsigned vb = x4[esrc0[j + 2] * 32 + l];
            a01a += up_lo(va); a23a += up_hi(va);
            a01b += up_lo(vb); a23b += up_hi(vb);
        }
        if (j < hi) {
            unsigned v = x4[esrc0[j] * 32 + l];
            a01a += up_lo(v); a23a += up_hi(v);
        }
        f32x2 a01 = a01a + a01b, a23 = a23a + a23b;
        a01.x += __shfl_down(a01.x, 32); a01.y += __shfl_down(a01.y, 32);
        a23.x += __shfl_down(a23.x, 32); a23.y += __shfl_down(a23.y, 32);
        if (half == 0) {
            float sc = rsqrtf(fmaxf((float)(hi - lo), 1.0f)) * (1.0f / X0S);
            uint2 o; o.x = pack2(a01.x * sc, a01.y * sc); o.y = pack2(a23.x * sc, a23.y * sc);
            *(uint2*)(A + w * 136 + l * 4) = o;        // 4 bf16 per lane
        }
    }
    __syncthreads();
    // ---- gemm phase: wave w -> col tile w (cols 16w..16w+15) ----
    int m = lane & 15, quad = lane >> 4;
    bf16x8 afr[4];
    #pragma unroll
    for (int ks = 0; ks < 4; ++ks)
        afr[ks] = *(const bf16x8*)(A + m * 136 + quad * 8 + ks * 32);
    int gcol0 = w * 16;
    const unsigned short* bbase = W1Tb + (gcol0 + m) * 128 + quad * 8;
    f32x4 acc = {0.f, 0.f, 0.f, 0.f};
    #pragma unroll
    for (int ks = 0; ks < 4; ++ks) {
        bf16x8 bfr = *(const bf16x8*)(bbase + ks * 32);
        acc = __builtin_amdgcn_mfma_f32_16x16x32_bf16(afr[ks], bfr, acc, 0, 0, 0);
    }
    int gcol = gcol0 + m;
    float bb = b1[gcol];
    #pragma unroll
    for (int reg = 0; reg < 4; ++reg) {
        int row = quad * 4 + reg;
        h1f[(row0 + row) * 256 + gcol] = f2fp8(fmaxf(acc[reg] + bb, 0.f) * s_out[row]);
    }
}

// ---------------- layer2: agg (16 waves, 1 dst/wave) + MFMA GEMM (+ labels), fused ----
__global__ void layer2_kernel(const int* __restrict__ off1, const int* __restrict__ esrc1,
                              const unsigned char* __restrict__ h1f,
                              const unsigned short* __restrict__ W2Tb,
                              const float* __restrict__ b2,
                              const int* __restrict__ labels,
                              float* __restrict__ out) {
    __shared__ unsigned short A[16 * 264];   // bf16 rows of 256, stride 264 (528B)
    int t = threadIdx.x;
    int row0 = blockIdx.x * 16;
    int w = t >> 6, lane = t & 63;
    // ---- agg phase: wave w -> dst row0 + w (64 lanes x uint = 256 fp8 row) ----
    {
        int d = row0 + w;
        f32x2 a01 = {0.f, 0.f}, a23 = {0.f, 0.f};
        float sc = 0.f;
        if (d < NDST1) {
            int lo = off1[d], hi = off1[d + 1];
            const unsigned* h4 = (const unsigned*)h1f;     // row = 64 uints
            int j = lo;
            for (; j + 3 < hi; j += 4) {                   // 4 loads in flight
                unsigned v0 = h4[esrc1[j] * 64 + lane];
                unsigned v1 = h4[esrc1[j + 1] * 64 + lane];
                unsigned v2 = h4[esrc1[j + 2] * 64 + lane];
                unsigned v3 = h4[esrc1[j + 3] * 64 + lane];
                a01 += up_lo(v0) + up_lo(v1) + up_lo(v2) + up_lo(v3);
                a23 += up_hi(v0) + up_hi(v1) + up_hi(v2) + up_hi(v3);
            }
            for (; j < hi; ++j) {
                unsigned v = h4[esrc1[j] * 64 + lane];
                a01 += up_lo(v); a23 += up_hi(v);
            }
            sc = rsqrtf(fmaxf((float)(hi - lo), 1.0f)) * (1.0f / H1S);
        }
        uint2 o; o.x = pack2(a01.x * sc, a01.y * sc); o.y = pack2(a23.x * sc, a23.y * sc);
        *(uint2*)(A + w * 264 + lane * 4) = o;
    }
    __syncthreads();
    if (w == 0) {                        // ---- gemm phase: single 16x16 tile ----
        int m = lane & 15, quad = lane >> 4;
        const unsigned short* bbase = W2Tb + m * 256 + quad * 8;
        f32x4 acc = {0.f, 0.f, 0.f, 0.f};
        #pragma unroll
        for (int ks = 0; ks < 8; ++ks) {
            bf16x8 af = *(const bf16x8*)(A + m * 264 + quad * 8 + ks * 32);
            bf16x8 bf = *(const bf16x8*)(bbase + ks * 32);
            acc = __builtin_amdgcn_mfma_f32_16x16x32_bf16(af, bf, acc, 0, 0, 0);
        }
        float bb = b2[m];
        #pragma unroll
        for (int reg = 0; reg < 4; ++reg) {
            int row = row0 + quad * 4 + reg;
            if (row < NDST1)
                out[row * NOUT + m] = fmaxf(acc[reg] + bb, 0.f);
        }
        if (lane < 16 && row0 + lane < NDST1)
            out[NDST1 * NOUT + row0 + lane] = (float)labels[row0 + lane];
    }
}

extern "C" void kernel_launch(void* const* d_in, const int* in_sizes, int n_in,
                              void* d_out, int out_size, void* d_ws, size_t ws_size,
                              hipStream_t stream) {
    const int*   user_word  = (const int*)d_in[0];
    const int*   labels     = (const int*)d_in[1];
    const int*   src0       = (const int*)d_in[2];
    const int*   dst0       = (const int*)d_in[3];
    const int*   src1       = (const int*)d_in[4];
    const int*   dst1       = (const int*)d_in[5];
    const float* word_table = (const float*)d_in[6];
    const float* W1         = (const float*)d_in[7];
    const float* b1         = (const float*)d_in[8];
    const float* W2         = (const float*)d_in[9];
    const float* b2         = (const float*)d_in[10];

    int* iws = (int*)d_ws;
    int* cnt0  = iws;            // 20000  ┐
    int* cnt1  = iws + 20000;    //  5000  │ zeroed (95000 ints)
    int* degO0 = iws + 25000;    // 50000  │
    int* degO1 = iws + 75000;    // 20000  ┘
    int* off0  = iws + 95000;    // 20001
    int* off1  = iws + 115001;   //  5001
    int* cur0  = iws + 120002;   // 20000
    int* cur1  = iws + 140002;   //  5000
    int* esrc0 = iws + 145002;   // 300000
    int* esrc1 = iws + 445002;   // 75000   (end 520002; pad to 520004)
    unsigned char*  wt8  = (unsigned char*)(iws + 520004);   // 6.4M fp8 (2 planes)
    unsigned char*  x0f  = (unsigned char*)(iws + 2120004);  // 6.4M fp8  = 1.6M ints
    unsigned char*  h1f  = (unsigned char*)(iws + 3720004);  // 5.12M fp8 = 1.28M ints
    unsigned short* W1Tb = (unsigned short*)(iws + 5000004); // 32768 bf16 = 8192 ints
    unsigned short* W2Tb = (unsigned short*)(iws + 5008196); // 4096 bf16 (end ≈ 20 MB)

    hipMemsetAsync(iws, 0, 95000 * sizeof(int), stream);

    prep_kernel<<<(NSRC0 * EMB / 8 + 255) / 256, 256, 0, stream>>>(
        word_table, wt8, W1, W1Tb, W2, W2Tb,
        src0, dst0, src1, dst1, cnt0, cnt1, degO0, degO1);
    scan_kernel<<<2, 1024, 0, stream>>>(cnt0, off0, cur0, cnt1, off1, cur1);
    embed_bucket_kernel<<<NEB2, 256, 0, stream>>>(
        user_word, wt8, degO0, x0f,
        src0, dst0, src1, dst1, cur0, cur1, esrc0, esrc1);
    layer1_kernel<<<NDST0 / 16, 1024, 0, stream>>>(off0, esrc0, x0f, degO1, W1Tb, b1, h1f);
    layer2_kernel<<<(NDST1 + 15) / 16, 1024, 0, stream>>>(off1, esrc1, h1f, W2Tb, b2,
                                                          labels, (float*)d_out);
}